// Round 6
// baseline (220.276 us; speedup 1.0000x reference)
//
#include <hip/hip_runtime.h>
#include <hip/hip_fp16.h>

#define B_ROWS 2048
#define C_COLS 65536
#define D_DIM  256
#define N_NEG  50
#define NTILES (C_COLS / 128)   // 512 column tiles

typedef __attribute__((ext_vector_type(8))) short short8;
typedef __attribute__((ext_vector_type(4))) float floatx4;
typedef __fp16 f16x2 __attribute__((ext_vector_type(2)));

__device__ __forceinline__ ushort f2bf(float f) {
  unsigned u = __float_as_uint(f);
  unsigned r = (u + 0x7FFFu + ((u >> 16) & 1u)) >> 16;  // RNE
  return (ushort)r;
}

__device__ __forceinline__ uint hmax2(uint a, uint b) {
  union { uint u; f16x2 h; } x, y, r;
  x.u = a; y.u = b;
  r.h = __builtin_elementwise_max(x.h, y.h);
  return r.u;
}

// ---------------- fp32 -> bf16 convert, K-block XOR swizzle (f only) ----
__global__ void cvt_swz(const float* __restrict__ in, ushort* __restrict__ out, int n8) {
  int i = blockIdx.x * blockDim.x + threadIdx.x;
  if (i >= n8) return;
  int row = i >> 5;
  int ka  = i & 31;
  int ktile = ka >> 3, kb = ka & 7;
  const float4* src = (const float4*)(in + (size_t)i * 8);
  float4 a = src[0], b = src[1];
  ushort4 o0, o1;
  o0.x = f2bf(a.x); o0.y = f2bf(a.y); o0.z = f2bf(a.z); o0.w = f2bf(a.w);
  o1.x = f2bf(b.x); o1.y = f2bf(b.y); o1.z = f2bf(b.z); o1.w = f2bf(b.w);
  ushort* dst = out + (size_t)row * D_DIM + ktile * 64 + ((kb ^ (row & 7)) << 3);
  ((ushort4*)dst)[0] = o0;
  ((ushort4*)dst)[1] = o1;
}

__device__ __forceinline__ void async16(const void* g, void* l) {
  __builtin_amdgcn_global_load_lds((const __attribute__((address_space(1))) void*)g,
                                   (__attribute__((address_space(3))) void*)l,
                                   16, 0, 0);
}

// ---------------- persistent-tile GEMM + fused cen convert + 16:1 group-max ----------------
// One block per column tile (512 blocks x 512 thr, 1 block/CU, 96KB LDS).
// Phase 0: convert cen tile [128][256] fp32->bf16 into LDS ONCE (amortized over 16 slabs).
// Main: 64 flat steps (16 slabs x 4 kt); stage only f chunk (16KB) dbuf'd, 1 barrier/step.
// Per-slab epilogue: in-register label mask + 16:1 group-max, direct global write.
__global__ __launch_bounds__(512, 2) void gemm_reduce(const ushort* __restrict__ fb,
                                                      const float* __restrict__ cen,
                                                      const int* __restrict__ label,
                                                      ushort* __restrict__ cand) {
  __shared__ __align__(16) ushort Cs[4 * 8192];   // cen bf16 [kt][128][64], swizzled kblks (64KB)
  __shared__ __align__(16) ushort Fs[2 * 8192];   // f dbuf [128][64], swizzled kblks (32KB)

  const int tid = threadIdx.x, wave = tid >> 6, lane = tid & 63;
  const int l = lane & 15, q = lane >> 4;

  // bijective XCD-chunk remap: XCD x owns tiles [x*64, x*64+64) -> disjoint cen slices per L2
  const int b = blockIdx.x;
  const int tile = (b & 7) * 64 + (b >> 3);
  const int n0 = tile << 7;

  // ---- phase 0: convert this tile's cen rows fp32 -> bf16 (once) ----
#pragma unroll
  for (int g = 0; g < 8; ++g) {
    int e = (g * 512 + tid) * 8;              // element in 128x256
    int row = e >> 8, k = e & 255;
    const float* gp = cen + (size_t)(n0 + row) * D_DIM + k;
    float4 fa = *(const float4*)gp;
    float4 fbv = *(const float4*)(gp + 4);
    int kt = k >> 6, kblk = (k >> 3) & 7;
    uint4 o;
    o.x = (uint)f2bf(fa.x)  | ((uint)f2bf(fa.y)  << 16);
    o.y = (uint)f2bf(fa.z)  | ((uint)f2bf(fa.w)  << 16);
    o.z = (uint)f2bf(fbv.x) | ((uint)f2bf(fbv.y) << 16);
    o.w = (uint)f2bf(fbv.z) | ((uint)f2bf(fbv.w) << 16);
    *(uint4*)(Cs + kt * 8192 + (row << 6) + ((kblk ^ (row & 7)) << 3)) = o;
  }

  // ---- prologue: stage step 0 (slab 0, kt 0) into buf 0 ----
#pragma unroll
  for (int r = 0; r < 2; ++r) {
    int idx = r * 4096 + wave * 512 + lane * 8;       // halves within 16KB chunk
    int row = idx >> 6, kk = idx & 63;
    async16(fb + (size_t)row * D_DIM + kk, Fs + r * 4096 + wave * 512);
  }
  __syncthreads();

  const int wn = (wave & 1) * 64, wm = (wave >> 1) * 32;

  for (int s = 0; s < 16; ++s) {
    floatx4 acc[4][2] = {};                    // [i: n-frag][j: m-frag]
    const int m0 = s << 7;
#pragma unroll
    for (int kt = 0; kt < 4; ++kt) {
      const int step = s * 4 + kt;
      if (step + 1 < 64) {                     // stage next chunk into other buffer
        const int ns = (step + 1) >> 2, nkt = (step + 1) & 3, nb = (step + 1) & 1;
#pragma unroll
        for (int r = 0; r < 2; ++r) {
          int idx = r * 4096 + wave * 512 + lane * 8;
          int row = idx >> 6, kk = idx & 63;
          async16(fb + (size_t)((ns << 7) + row) * D_DIM + nkt * 64 + kk,
                  Fs + nb * 8192 + r * 4096 + wave * 512);
        }
      }
      const ushort* Cb = Cs + kt * 8192;
      const ushort* Fb = Fs + (step & 1) * 8192;
#pragma unroll
      for (int ks = 0; ks < 2; ++ks) {
        short8 a[4], bb[2];
        int swz = ((4 * ks + q) ^ (l & 7)) << 3;
#pragma unroll
        for (int i = 0; i < 4; ++i)
          a[i] = *(const short8*)(Cb + ((wn + i * 16 + l) << 6) + swz);
#pragma unroll
        for (int j = 0; j < 2; ++j)
          bb[j] = *(const short8*)(Fb + ((wm + j * 16 + l) << 6) + swz);
#pragma unroll
        for (int i = 0; i < 4; ++i)
#pragma unroll
          for (int j = 0; j < 2; ++j)
            acc[i][j] = __builtin_amdgcn_mfma_f32_16x16x32_bf16(a[i], bb[j], acc[i][j], 0, 0, 0);
      }
      __syncthreads();   // staged next visible; all waves done with current buf
    }

    // ---- epilogue slab s: label mask + 16:1 group-max, regs -> global ----
    // lane holds D[n][m]: n_local = wn + i*16 + q*4 + r, m_local = wm + j*16 + l.
    int lj[2];
#pragma unroll
    for (int j = 0; j < 2; ++j) lj[j] = label[m0 + wm + j * 16 + l] - n0 - wn;
    bool hit = ((unsigned)lj[0] < 64u) || ((unsigned)lj[1] < 64u);
    if (__any(hit)) {          // rare: mask positive column pre-max
#pragma unroll
      for (int j = 0; j < 2; ++j) {
        int relq = lj[j] - q * 4;
#pragma unroll
        for (int i = 0; i < 4; ++i) {
          int rel = relq - i * 16;
#pragma unroll
          for (int r = 0; r < 4; ++r)
            if (rel == r) acc[i][j][r] = -INFINITY;
        }
      }
    }
#pragma unroll
    for (int j = 0; j < 2; ++j) {
      float mx[4];
#pragma unroll
      for (int i = 0; i < 4; ++i)
        mx[i] = fmaxf(fmaxf(acc[i][j][0], acc[i][j][1]),
                      fmaxf(acc[i][j][2], acc[i][j][3]));
      union { f16x2 h; uint u; } c0, c1;
      c0.h = __builtin_amdgcn_cvt_pkrtz(mx[0], mx[1]);
      c1.h = __builtin_amdgcn_cvt_pkrtz(mx[2], mx[3]);
      uint u01 = c0.u, u23 = c1.u;
      u01 = hmax2(u01, __shfl_xor(u01, 16));
      u01 = hmax2(u01, __shfl_xor(u01, 32));
      u23 = hmax2(u23, __shfl_xor(u23, 16));
      u23 = hmax2(u23, __shfl_xor(u23, 32));
      if (q == 0) {
        uint2 w; w.x = u01; w.y = u23;
        // [tile][row][8] fp16; wn half selects 8B slot; both halves written in-block.
        *(uint2*)(cand + ((size_t)tile * B_ROWS + m0 + wm + j * 16 + l) * 8 + (wn >> 4)) = w;
      }
    }
  }
}

// fp16-bit monotone key <-> value
__device__ __forceinline__ float dec_key(int k) {
  if (k < 0x0400) return -INFINITY;
  ushort h = (k >= 0x8000) ? (ushort)(k ^ 0x8000) : (ushort)(~k & 0xFFFF);
  __half_raw hr; hr.x = h;
  return __half2float((__half)hr);
}

// ---------------- per-row top-50 + loss: one wave per row (refcheck'd round 4) ----
__global__ __launch_bounds__(512) void final_select(const ushort* __restrict__ cand,
                                                    const float* __restrict__ f,
                                                    const float* __restrict__ cen,
                                                    const int* __restrict__ label,
                                                    float* __restrict__ rowloss) {
  __shared__ __align__(16) uint4 ST[NTILES][8];   // 64 KB, slot swizzled by tile&7
  const int tid = threadIdx.x;
  const int lane = tid & 63, w = tid >> 6;
  const int row0 = blockIdx.x * 8;

  const uint4* p = (const uint4*)cand;
#pragma unroll
  for (int k = 0; k < 8; ++k) {
    int j = k * 512 + tid;
    int tile = j >> 3, rr = j & 7;
    ST[tile][rr ^ (tile & 7)] = p[(size_t)tile * B_ROWS + row0 + rr];
  }
  __syncthreads();

  const int row = row0 + w;
  const int lab = label[row];

  float v[64];
#pragma unroll
  for (int c = 0; c < 8; ++c) {
    int tile = c * 64 + lane;
    uint4 u = ST[tile][w ^ (tile & 7)];
    union { uint u; f16x2 h; } cv;
    cv.u = u.x; v[c * 8 + 0] = (float)cv.h.x; v[c * 8 + 1] = (float)cv.h.y;
    cv.u = u.y; v[c * 8 + 2] = (float)cv.h.x; v[c * 8 + 3] = (float)cv.h.y;
    cv.u = u.z; v[c * 8 + 4] = (float)cv.h.x; v[c * 8 + 5] = (float)cv.h.y;
    cv.u = u.w; v[c * 8 + 6] = (float)cv.h.x; v[c * 8 + 7] = (float)cv.h.y;
  }

  float4 fv = *(const float4*)(f   + (size_t)row * D_DIM + lane * 4);
  float4 cv4 = *(const float4*)(cen + (size_t)lab * D_DIM + lane * 4);
  float pv = fv.x * cv4.x + fv.y * cv4.y + fv.z * cv4.z + fv.w * cv4.w;

  float m = v[0];
#pragma unroll
  for (int k = 1; k < 64; ++k) m = fmaxf(m, v[k]);
#pragma unroll
  for (int o = 32; o > 0; o >>= 1) {
    m = fmaxf(m, __shfl_xor(m, o));
    pv += __shfl_xor(pv, o);
  }
  const float pos = pv;

  __half hm = __float2half(m);
  int hb = (int)(*(ushort*)&hm);
  int km = (m >= 0.f) ? (0x8000 | hb) : (~hb & 0xFFFF);
  int lo = km - 2048, hi = km;
  if (lo < 0x0400) lo = 0x0400;
  for (int it = 0; it < 12; ++it) {
    int mid = (lo + hi) >> 1;
    float tau = dec_key(mid);
    int c = 0;
#pragma unroll
    for (int k = 0; k < 64; ++k) c += (v[k] > tau) ? 1 : 0;
#pragma unroll
    for (int o = 32; o > 0; o >>= 1) c += __shfl_xor(c, o);
    if (c <= 49) hi = mid; else lo = mid + 1;
  }

  const float tau = dec_key(hi);
  float sum = 0.f, se = 0.f; int c = 0;
#pragma unroll
  for (int k = 0; k < 64; ++k) {
    if (v[k] > tau) { ++c; sum += v[k]; se += expf(v[k] - m); }
  }
#pragma unroll
  for (int o = 32; o > 0; o >>= 1) {
    sum += __shfl_xor(sum, o);
    se  += __shfl_xor(se, o);
    c   += __shfl_xor(c, o);
  }
  if (lane == 0) {
    float nfill = (float)(N_NEG - c);
    float S = sum + nfill * tau;
    float E = se + nfill * expf(tau - m);
    float M = fmaxf(m, pos);
    float seAll = E * expf(m - M) + expf(pos - M);
    float lse = M + logf(seAll);
    rowloss[row] = 0.9102f * lse - 0.9002f * pos - 2.0e-4f * S;
  }
}

__global__ void sum_loss(const float* __restrict__ rowloss, float* __restrict__ out) {
  __shared__ float red[4];
  const int tid = threadIdx.x;
  float s = 0.f;
  for (int i = tid; i < B_ROWS; i += 256) s += rowloss[i];
#pragma unroll
  for (int o = 32; o > 0; o >>= 1) s += __shfl_down(s, o);
  if ((tid & 63) == 0) red[tid >> 6] = s;
  __syncthreads();
  if (tid == 0) out[0] = (red[0] + red[1] + red[2] + red[3]) * (1.0f / B_ROWS);
}

extern "C" void kernel_launch(void* const* d_in, const int* in_sizes, int n_in,
                              void* d_out, int out_size, void* d_ws, size_t ws_size,
                              hipStream_t stream) {
  const float* f   = (const float*)d_in[0];
  const float* cen = (const float*)d_in[1];
  const int*   label = (const int*)d_in[2];
  float* out = (float*)d_out;

  char* ws = (char*)d_ws;
  ushort* cand    = (ushort*)ws;                      // 16 MiB: [512 tiles][2048 rows][8] fp16
  ushort* fb      = (ushort*)(ws + 16777216);         // 1 MiB
  float*  rowloss = (float*)(ws + 17825792);          // 8 KiB

  cvt_swz<<<256, 256, 0, stream>>>(f, fb, (B_ROWS * D_DIM) / 8);

  gemm_reduce<<<NTILES, 512, 0, stream>>>(fb, cen, label, cand);

  final_select<<<B_ROWS / 8, 512, 0, stream>>>(cand, f, cen, label, rowloss);
  sum_loss<<<1, 256, 0, stream>>>(rowloss, out);
}

// Round 7
// 196.610 us; speedup vs baseline: 1.1204x; 1.1204x over previous
//
#include <hip/hip_runtime.h>
#include <hip/hip_fp16.h>

#define B_ROWS 2048
#define C_COLS 65536
#define D_DIM  256
#define N_NEG  50
#define NTILES (C_COLS / 128)   // 512 column tiles

typedef __attribute__((ext_vector_type(8))) short short8;
typedef __attribute__((ext_vector_type(4))) float floatx4;
typedef __fp16 f16x2 __attribute__((ext_vector_type(2)));

__device__ __forceinline__ ushort f2bf(float f) {
  unsigned u = __float_as_uint(f);
  unsigned r = (u + 0x7FFFu + ((u >> 16) & 1u)) >> 16;  // RNE
  return (ushort)r;
}

__device__ __forceinline__ uint hmax2(uint a, uint b) {
  union { uint u; f16x2 h; } x, y, r;
  x.u = a; y.u = b;
  r.h = __builtin_elementwise_max(x.h, y.h);
  return r.u;
}

// ---------------- fp32 -> bf16 convert, K-block XOR swizzle in global layout ----
__device__ __forceinline__ void cvt8(const float* __restrict__ in, ushort* __restrict__ out,
                                     int i) {
  int row = i >> 5;
  int ka  = i & 31;
  int ktile = ka >> 3, kb = ka & 7;
  const float4* src = (const float4*)(in + (size_t)i * 8);
  float4 a = src[0], b = src[1];
  ushort4 o0, o1;
  o0.x = f2bf(a.x); o0.y = f2bf(a.y); o0.z = f2bf(a.z); o0.w = f2bf(a.w);
  o1.x = f2bf(b.x); o1.y = f2bf(b.y); o1.z = f2bf(b.z); o1.w = f2bf(b.w);
  ushort* dst = out + (size_t)row * D_DIM + ktile * 64 + ((kb ^ (row & 7)) << 3);
  ((ushort4*)dst)[0] = o0;
  ((ushort4*)dst)[1] = o1;
}

// one dispatch: blocks [0,256) convert f -> fb, blocks [256,8448) convert cen -> cb.
// block 0 also zero-inits the loss accumulator + completion counter (FS runs later in
// stream order, so visibility is guaranteed at the kernel boundary).
__global__ void cvt_all(const float* __restrict__ f, ushort* __restrict__ fb,
                        const float* __restrict__ cen, ushort* __restrict__ cb,
                        float* __restrict__ accum, unsigned int* __restrict__ counter) {
  const int b = blockIdx.x, tid = threadIdx.x;
  if (b == 0 && tid == 0) { *accum = 0.f; *counter = 0u; }
  if (b < 256) {
    int i = b * 256 + tid;
    if (i < (B_ROWS * D_DIM) / 8) cvt8(f, fb, i);
  } else {
    int i = (b - 256) * 256 + tid;
    if (i < (C_COLS * D_DIM) / 8) cvt8(cen, cb, i);
  }
}

__device__ __forceinline__ void async16(const void* g, void* l) {
  __builtin_amdgcn_global_load_lds((const __attribute__((address_space(1))) void*)g,
                                   (__attribute__((address_space(3))) void*)l,
                                   16, 0, 0);
}

// ---------------- GEMM (D[n][m]) + in-register 16:1 group-max reduction ----------------
// (byte-identical to round 3/4 core: 74us, MfmaUtil 39%, FETCH 20.6MB, WRITE 16.4MB)
template <bool PREB>
__global__ void gemm_reduce(const ushort* __restrict__ fb,
                            const ushort* __restrict__ cb,
                            const float* __restrict__ cen,
                            const int* __restrict__ label,
                            ushort* __restrict__ cand) {
  __shared__ __align__(16) ushort Cs[128 * 64];   // cen bf16 [128][64], swizzled kblks
  __shared__ __align__(16) ushort Fs[128 * 64];   // f   bf16 [128][64], swizzled kblks
  __shared__ __align__(16) ushort gm[128][8];     // fp16 group-max [m][group]
  __shared__ int labLDS[128];

  const int tid = threadIdx.x, wave = tid >> 6, lane = tid & 63;
  const int l = lane & 15, q = lane >> 4;

  // bijective XCD-chunk remap (8192 blocks, 8 XCDs, 1024 each; slab-fastest inside)
  const int lin = blockIdx.y * 16 + blockIdx.x;
  const int lg  = (lin & 7) * 1024 + (lin >> 3);
  const int m0 = (lg & 15) << 7;
  const int bxTile = lg >> 4;
  const int n0 = bxTile << 7;
  if (tid < 128) labLDS[tid] = label[m0 + tid];

  floatx4 acc[4][4] = {};               // [i: n-block][j: m-block]
  const int wn = (wave >> 1) * 64, wm = (wave & 1) * 64;

  for (int kt = 0; kt < D_DIM / 64; ++kt) {
#pragma unroll
    for (int r = 0; r < 4; ++r) {
      int idx = r * 2048 + wave * 512 + lane * 8;
      int row = idx >> 6, kk = idx & 63;
      async16(fb + (size_t)(m0 + row) * D_DIM + kt * 64 + kk, Fs + r * 2048 + wave * 512);
      if (PREB)
        async16(cb + (size_t)(n0 + row) * D_DIM + kt * 64 + kk, Cs + r * 2048 + wave * 512);
    }
    if (!PREB) {
      float4 ra[4], rb[4];
#pragma unroll
      for (int g = 0; g < 4; ++g) {
        int e = (tid + g * 256) * 8;
        const float* gp = cen + (size_t)(n0 + (e >> 6)) * D_DIM + kt * 64 + (e & 63);
        ra[g] = *(const float4*)gp;
        rb[g] = *(const float4*)(gp + 4);
      }
#pragma unroll
      for (int g = 0; g < 4; ++g) {
        int e = (tid + g * 256) * 8;
        int row = e >> 6, kblk = (e >> 3) & 7;
        uint4 o;
        o.x = (uint)f2bf(ra[g].x) | ((uint)f2bf(ra[g].y) << 16);
        o.y = (uint)f2bf(ra[g].z) | ((uint)f2bf(ra[g].w) << 16);
        o.z = (uint)f2bf(rb[g].x) | ((uint)f2bf(rb[g].y) << 16);
        o.w = (uint)f2bf(rb[g].z) | ((uint)f2bf(rb[g].w) << 16);
        *(uint4*)(Cs + (row << 6) + ((kblk ^ (row & 7)) << 3)) = o;
      }
    }
    __syncthreads();

#pragma unroll
    for (int ks = 0; ks < 2; ++ks) {
      short8 a[4], b[4];
#pragma unroll
      for (int i = 0; i < 4; ++i) {
        int swz = ((4 * ks + q) ^ (l & 7)) << 3;
        a[i] = *(const short8*)(Cs + ((wn + i * 16 + l) << 6) + swz);
        b[i] = *(const short8*)(Fs + ((wm + i * 16 + l) << 6) + swz);
      }
#pragma unroll
      for (int i = 0; i < 4; ++i)
#pragma unroll
        for (int j = 0; j < 4; ++j)
          acc[i][j] = __builtin_amdgcn_mfma_f32_16x16x32_bf16(a[i], b[j], acc[i][j], 0, 0, 0);
    }
    __syncthreads();
  }

  // ---- epilogue: in-register label mask + 16:1 group-max ----
  int lj[4];
#pragma unroll
  for (int j = 0; j < 4; ++j) lj[j] = labLDS[wm + j * 16 + l] - n0 - wn;
  bool hit = false;
#pragma unroll
  for (int j = 0; j < 4; ++j) hit = hit || ((unsigned)lj[j] < 64u);
  if (__any(hit)) {
#pragma unroll
    for (int j = 0; j < 4; ++j) {
      int relq = lj[j] - q * 4;
#pragma unroll
      for (int i = 0; i < 4; ++i) {
        int rel = relq - i * 16;
#pragma unroll
        for (int r = 0; r < 4; ++r)
          if (rel == r) acc[i][j][r] = -INFINITY;
      }
    }
  }
#pragma unroll
  for (int j = 0; j < 4; ++j) {
    float mx[4];
#pragma unroll
    for (int i = 0; i < 4; ++i)
      mx[i] = fmaxf(fmaxf(acc[i][j][0], acc[i][j][1]),
                    fmaxf(acc[i][j][2], acc[i][j][3]));
    union { f16x2 h; uint u; } c0, c1;
    c0.h = __builtin_amdgcn_cvt_pkrtz(mx[0], mx[1]);
    c1.h = __builtin_amdgcn_cvt_pkrtz(mx[2], mx[3]);
    uint u01 = c0.u, u23 = c1.u;
    u01 = hmax2(u01, __shfl_xor(u01, 16));
    u01 = hmax2(u01, __shfl_xor(u01, 32));
    u23 = hmax2(u23, __shfl_xor(u23, 16));
    u23 = hmax2(u23, __shfl_xor(u23, 32));
    if (q == 0) {
      uint2 w; w.x = u01; w.y = u23;
      *(uint2*)&gm[wm + j * 16 + l][wn >> 4] = w;
    }
  }
  __syncthreads();
  // [tile][row][8] fp16: 128 x 16B = contiguous 2KB burst per block, full lines.
  if (tid < 128) {
    uint4 w = *(const uint4*)&gm[tid][0];
    *(uint4*)(cand + ((size_t)bxTile * B_ROWS + (m0 + tid)) * 8) = w;
  }
}

// fp16-bit monotone key <-> value
__device__ __forceinline__ float dec_key(int k) {
  if (k < 0x0400) return -INFINITY;
  ushort h = (k >= 0x8000) ? (ushort)(k ^ 0x8000) : (ushort)(~k & 0xFFFF);
  __half_raw hr; hr.x = h;
  return __half2float((__half)hr);
}

// ---------------- per-row top-50 + loss (one wave/row) + fused grid reduction ----
// 256 blocks x 512 threads. Each block sums its 8 rowlosses, atomicAdds the partial
// (device-scope), and the last-arriving block writes the mean to out.
__global__ __launch_bounds__(512) void final_select(const ushort* __restrict__ cand,
                                                    const float* __restrict__ f,
                                                    const float* __restrict__ cen,
                                                    const int* __restrict__ label,
                                                    float* __restrict__ accum,
                                                    unsigned int* __restrict__ counter,
                                                    float* __restrict__ out) {
  __shared__ __align__(16) uint4 ST[NTILES][8];   // 64 KB, slot swizzled by tile&7
  __shared__ float sblk[8];
  const int tid = threadIdx.x;
  const int lane = tid & 63, w = tid >> 6;
  const int row0 = blockIdx.x * 8;

  const uint4* p = (const uint4*)cand;
#pragma unroll
  for (int k = 0; k < 8; ++k) {
    int j = k * 512 + tid;
    int tile = j >> 3, rr = j & 7;
    ST[tile][rr ^ (tile & 7)] = p[(size_t)tile * B_ROWS + row0 + rr];
  }
  __syncthreads();

  const int row = row0 + w;
  const int lab = label[row];

  float v[64];
#pragma unroll
  for (int c = 0; c < 8; ++c) {
    int tile = c * 64 + lane;
    uint4 u = ST[tile][w ^ (tile & 7)];
    union { uint u; f16x2 h; } cv;
    cv.u = u.x; v[c * 8 + 0] = (float)cv.h.x; v[c * 8 + 1] = (float)cv.h.y;
    cv.u = u.y; v[c * 8 + 2] = (float)cv.h.x; v[c * 8 + 3] = (float)cv.h.y;
    cv.u = u.z; v[c * 8 + 4] = (float)cv.h.x; v[c * 8 + 5] = (float)cv.h.y;
    cv.u = u.w; v[c * 8 + 6] = (float)cv.h.x; v[c * 8 + 7] = (float)cv.h.y;
  }

  float4 fv = *(const float4*)(f   + (size_t)row * D_DIM + lane * 4);
  float4 cv4 = *(const float4*)(cen + (size_t)lab * D_DIM + lane * 4);
  float pv = fv.x * cv4.x + fv.y * cv4.y + fv.z * cv4.z + fv.w * cv4.w;

  float m = v[0];
#pragma unroll
  for (int k = 1; k < 64; ++k) m = fmaxf(m, v[k]);
#pragma unroll
  for (int o = 32; o > 0; o >>= 1) {
    m = fmaxf(m, __shfl_xor(m, o));
    pv += __shfl_xor(pv, o);
  }
  const float pos = pv;

  // bisection seeded at the row max key: answer lies within ~300 keys; 2048 is ample
  __half hm = __float2half(m);
  int hb = (int)(*(ushort*)&hm);
  int km = (m >= 0.f) ? (0x8000 | hb) : (~hb & 0xFFFF);
  int lo = km - 2048, hi = km;
  if (lo < 0x0400) lo = 0x0400;
  for (int it = 0; it < 12; ++it) {
    int mid = (lo + hi) >> 1;
    float tau = dec_key(mid);
    int c = 0;
#pragma unroll
    for (int k = 0; k < 64; ++k) c += (v[k] > tau) ? 1 : 0;
#pragma unroll
    for (int o = 32; o > 0; o >>= 1) c += __shfl_xor(c, o);
    if (c <= 49) hi = mid; else lo = mid + 1;
  }

  const float tau = dec_key(hi);
  float sum = 0.f, se = 0.f; int c = 0;
#pragma unroll
  for (int k = 0; k < 64; ++k) {
    if (v[k] > tau) { ++c; sum += v[k]; se += expf(v[k] - m); }
  }
#pragma unroll
  for (int o = 32; o > 0; o >>= 1) {
    sum += __shfl_xor(sum, o);
    se  += __shfl_xor(se, o);
    c   += __shfl_xor(c, o);
  }
  if (lane == 0) {
    float nfill = (float)(N_NEG - c);
    float S = sum + nfill * tau;
    float E = se + nfill * expf(tau - m);
    float M = fmaxf(m, pos);
    float seAll = E * expf(m - M) + expf(pos - M);
    float lse = M + logf(seAll);
    sblk[w] = 0.9102f * lse - 0.9002f * pos - 2.0e-4f * S;
  }
  __syncthreads();
  if (tid == 0) {
    float part = 0.f;
#pragma unroll
    for (int i = 0; i < 8; ++i) part += sblk[i];
    atomicAdd(accum, part);
    __threadfence();
    unsigned int old = atomicAdd(counter, 1u);
    if (old == gridDim.x - 1) {
      float s = atomicAdd(accum, 0.0f);   // atomic read: sees all prior adds
      out[0] = s * (1.0f / B_ROWS);
    }
  }
}

extern "C" void kernel_launch(void* const* d_in, const int* in_sizes, int n_in,
                              void* d_out, int out_size, void* d_ws, size_t ws_size,
                              hipStream_t stream) {
  const float* f   = (const float*)d_in[0];
  const float* cen = (const float*)d_in[1];
  const int*   label = (const int*)d_in[2];
  float* out = (float*)d_out;

  char* ws = (char*)d_ws;
  ushort* cand    = (ushort*)ws;                      // 16 MiB: [512 tiles][2048 rows][8] fp16
  ushort* fb      = (ushort*)(ws + 16777216);         // 1 MiB
  float*  accum   = (float*)(ws + 17825792);          // 4 B loss accumulator
  unsigned int* counter = (unsigned int*)(ws + 17825796);  // 4 B completion counter
  ushort* cb      = (ushort*)(ws + 17833984);         // 32 MiB (fast path)
  const bool pre = ws_size >= (17833984ull + 33554432ull);

  dim3 grid(B_ROWS / 128, NTILES);  // XCD-chunk swizzled inside the kernel
  if (pre) {
    cvt_all<<<8448, 256, 0, stream>>>(f, fb, cen, cb, accum, counter);
    gemm_reduce<true><<<grid, 256, 0, stream>>>(fb, cb, nullptr, label, cand);
  } else {
    cvt_all<<<256, 256, 0, stream>>>(f, fb, nullptr, nullptr, accum, counter);
    gemm_reduce<false><<<grid, 256, 0, stream>>>(fb, nullptr, cen, label, cand);
  }

  final_select<<<B_ROWS / 8, 512, 0, stream>>>(cand, f, cen, label, accum, counter, out);
}

// Round 8
// 189.452 us; speedup vs baseline: 1.1627x; 1.0378x over previous
//
#include <hip/hip_runtime.h>
#include <hip/hip_fp16.h>

#define B_ROWS 2048
#define C_COLS 65536
#define D_DIM  256
#define N_NEG  50
#define NTILES (C_COLS / 128)   // 512 column tiles

typedef __attribute__((ext_vector_type(8))) short short8;
typedef __attribute__((ext_vector_type(4))) float floatx4;
typedef __fp16 f16x2 __attribute__((ext_vector_type(2)));

__device__ __forceinline__ ushort f2bf(float f) {
  unsigned u = __float_as_uint(f);
  unsigned r = (u + 0x7FFFu + ((u >> 16) & 1u)) >> 16;  // RNE
  return (ushort)r;
}

__device__ __forceinline__ uint hmax2(uint a, uint b) {
  union { uint u; f16x2 h; } x, y, r;
  x.u = a; y.u = b;
  r.h = __builtin_elementwise_max(x.h, y.h);
  return r.u;
}

// ---------------- fp32 -> bf16 convert, K-block XOR swizzle in global layout ----
__device__ __forceinline__ void cvt8(const float* __restrict__ in, ushort* __restrict__ out,
                                     int i) {
  int row = i >> 5;
  int ka  = i & 31;
  int ktile = ka >> 3, kb = ka & 7;
  const float4* src = (const float4*)(in + (size_t)i * 8);
  float4 a = src[0], b = src[1];
  ushort4 o0, o1;
  o0.x = f2bf(a.x); o0.y = f2bf(a.y); o0.z = f2bf(a.z); o0.w = f2bf(a.w);
  o1.x = f2bf(b.x); o1.y = f2bf(b.y); o1.z = f2bf(b.z); o1.w = f2bf(b.w);
  ushort* dst = out + (size_t)row * D_DIM + ktile * 64 + ((kb ^ (row & 7)) << 3);
  ((ushort4*)dst)[0] = o0;
  ((ushort4*)dst)[1] = o1;
}

// one dispatch: blocks [0,256) convert f -> fb, blocks [256,8448) convert cen -> cb.
// block 0 also zero-inits the loss accumulator + completion counter.
__global__ void cvt_all(const float* __restrict__ f, ushort* __restrict__ fb,
                        const float* __restrict__ cen, ushort* __restrict__ cb,
                        float* __restrict__ accum, unsigned int* __restrict__ counter) {
  const int b = blockIdx.x, tid = threadIdx.x;
  if (b == 0 && tid == 0) { *accum = 0.f; *counter = 0u; }
  if (b < 256) {
    int i = b * 256 + tid;
    if (i < (B_ROWS * D_DIM) / 8) cvt8(f, fb, i);
  } else {
    int i = (b - 256) * 256 + tid;
    if (i < (C_COLS * D_DIM) / 8) cvt8(cen, cb, i);
  }
}

__device__ __forceinline__ void async16(const void* g, void* l) {
  __builtin_amdgcn_global_load_lds((const __attribute__((address_space(1))) void*)g,
                                   (__attribute__((address_space(3))) void*)l,
                                   16, 0, 0);
}

// ---------------- GEMM (D[n][m]) + in-register 16:1 group-max reduction ----------------
// R3/R4 core (74us, MfmaUtil 39%) with LDS diet: exactly 32KB (Cs+Fs only) -> 5 blocks/CU.
// Epilogue writes group-maxes reg->global uint2 (validated R6) and reads labels from
// global directly (8KB, L2-hot) instead of LDS staging.
template <bool PREB>
__global__ void gemm_reduce(const ushort* __restrict__ fb,
                            const ushort* __restrict__ cb,
                            const float* __restrict__ cen,
                            const int* __restrict__ label,
                            ushort* __restrict__ cand) {
  __shared__ __align__(16) ushort Cs[128 * 64];   // cen bf16 [128][64], swizzled kblks
  __shared__ __align__(16) ushort Fs[128 * 64];   // f   bf16 [128][64], swizzled kblks

  const int tid = threadIdx.x, wave = tid >> 6, lane = tid & 63;
  const int l = lane & 15, q = lane >> 4;

  // bijective XCD-chunk remap (8192 blocks, 8 XCDs, 1024 each; slab-fastest inside)
  const int lin = blockIdx.y * 16 + blockIdx.x;
  const int lg  = (lin & 7) * 1024 + (lin >> 3);
  const int m0 = (lg & 15) << 7;
  const int bxTile = lg >> 4;
  const int n0 = bxTile << 7;

  floatx4 acc[4][4] = {};               // [i: n-block][j: m-block]
  const int wn = (wave >> 1) * 64, wm = (wave & 1) * 64;

  for (int kt = 0; kt < D_DIM / 64; ++kt) {
#pragma unroll
    for (int r = 0; r < 4; ++r) {
      int idx = r * 2048 + wave * 512 + lane * 8;
      int row = idx >> 6, kk = idx & 63;
      async16(fb + (size_t)(m0 + row) * D_DIM + kt * 64 + kk, Fs + r * 2048 + wave * 512);
      if (PREB)
        async16(cb + (size_t)(n0 + row) * D_DIM + kt * 64 + kk, Cs + r * 2048 + wave * 512);
    }
    if (!PREB) {
      float4 ra[4], rb[4];
#pragma unroll
      for (int g = 0; g < 4; ++g) {
        int e = (tid + g * 256) * 8;
        const float* gp = cen + (size_t)(n0 + (e >> 6)) * D_DIM + kt * 64 + (e & 63);
        ra[g] = *(const float4*)gp;
        rb[g] = *(const float4*)(gp + 4);
      }
#pragma unroll
      for (int g = 0; g < 4; ++g) {
        int e = (tid + g * 256) * 8;
        int row = e >> 6, kblk = (e >> 3) & 7;
        uint4 o;
        o.x = (uint)f2bf(ra[g].x) | ((uint)f2bf(ra[g].y) << 16);
        o.y = (uint)f2bf(ra[g].z) | ((uint)f2bf(ra[g].w) << 16);
        o.z = (uint)f2bf(rb[g].x) | ((uint)f2bf(rb[g].y) << 16);
        o.w = (uint)f2bf(rb[g].z) | ((uint)f2bf(rb[g].w) << 16);
        *(uint4*)(Cs + (row << 6) + ((kblk ^ (row & 7)) << 3)) = o;
      }
    }
    __syncthreads();

#pragma unroll
    for (int ks = 0; ks < 2; ++ks) {
      short8 a[4], b[4];
#pragma unroll
      for (int i = 0; i < 4; ++i) {
        int swz = ((4 * ks + q) ^ (l & 7)) << 3;
        a[i] = *(const short8*)(Cs + ((wn + i * 16 + l) << 6) + swz);
        b[i] = *(const short8*)(Fs + ((wm + i * 16 + l) << 6) + swz);
      }
#pragma unroll
      for (int i = 0; i < 4; ++i)
#pragma unroll
        for (int j = 0; j < 4; ++j)
          acc[i][j] = __builtin_amdgcn_mfma_f32_16x16x32_bf16(a[i], b[j], acc[i][j], 0, 0, 0);
    }
    __syncthreads();
  }

  // ---- epilogue: in-register label mask + 16:1 group-max, reg->global ----
  // lane holds D[n][m]: n_local = wn + i*16 + q*4 + r, m_local = wm + j*16 + l.
  int lj[4];
#pragma unroll
  for (int j = 0; j < 4; ++j) lj[j] = label[m0 + wm + j * 16 + l] - n0 - wn;
  bool hit = false;
#pragma unroll
  for (int j = 0; j < 4; ++j) hit = hit || ((unsigned)lj[j] < 64u);
  if (__any(hit)) {            // rare: mask positive column pre-max
#pragma unroll
    for (int j = 0; j < 4; ++j) {
      int relq = lj[j] - q * 4;
#pragma unroll
      for (int i = 0; i < 4; ++i) {
        int rel = relq - i * 16;
#pragma unroll
        for (int r = 0; r < 4; ++r)
          if (rel == r) acc[i][j][r] = -INFINITY;
      }
    }
  }
  // frag (i,j) covers exactly group (wn>>4)+i for 16 m's; reduce 4 regs in-lane,
  // then across q (lanes ^16, ^32) on RTZ-packed fp16 (monotone under max).
#pragma unroll
  for (int j = 0; j < 4; ++j) {
    float mx[4];
#pragma unroll
    for (int i = 0; i < 4; ++i)
      mx[i] = fmaxf(fmaxf(acc[i][j][0], acc[i][j][1]),
                    fmaxf(acc[i][j][2], acc[i][j][3]));
    union { f16x2 h; uint u; } c0, c1;
    c0.h = __builtin_amdgcn_cvt_pkrtz(mx[0], mx[1]);
    c1.h = __builtin_amdgcn_cvt_pkrtz(mx[2], mx[3]);
    uint u01 = c0.u, u23 = c1.u;
    u01 = hmax2(u01, __shfl_xor(u01, 16));
    u01 = hmax2(u01, __shfl_xor(u01, 32));
    u23 = hmax2(u23, __shfl_xor(u23, 16));
    u23 = hmax2(u23, __shfl_xor(u23, 32));
    if (q == 0) {
      uint2 w; w.x = u01; w.y = u23;
      // [tile][row][8] fp16; wn selects the 4-group half; both halves written in-block.
      *(uint2*)(cand + ((size_t)bxTile * B_ROWS + m0 + wm + j * 16 + l) * 8 + (wn >> 4)) = w;
    }
  }
}

// fp16-bit monotone key <-> value
__device__ __forceinline__ float dec_key(int k) {
  if (k < 0x0400) return -INFINITY;
  ushort h = (k >= 0x8000) ? (ushort)(k ^ 0x8000) : (ushort)(~k & 0xFFFF);
  __half_raw hr; hr.x = h;
  return __half2float((__half)hr);
}

// ---------------- per-row top-50 + loss (one wave/row) + fused grid reduction ----
__global__ __launch_bounds__(512) void final_select(const ushort* __restrict__ cand,
                                                    const float* __restrict__ f,
                                                    const float* __restrict__ cen,
                                                    const int* __restrict__ label,
                                                    float* __restrict__ accum,
                                                    unsigned int* __restrict__ counter,
                                                    float* __restrict__ out) {
  __shared__ __align__(16) uint4 ST[NTILES][8];   // 64 KB, slot swizzled by tile&7
  __shared__ float sblk[8];
  const int tid = threadIdx.x;
  const int lane = tid & 63, w = tid >> 6;
  const int row0 = blockIdx.x * 8;

  const uint4* p = (const uint4*)cand;
#pragma unroll
  for (int k = 0; k < 8; ++k) {
    int j = k * 512 + tid;
    int tile = j >> 3, rr = j & 7;
    ST[tile][rr ^ (tile & 7)] = p[(size_t)tile * B_ROWS + row0 + rr];
  }
  __syncthreads();

  const int row = row0 + w;
  const int lab = label[row];

  float v[64];
#pragma unroll
  for (int c = 0; c < 8; ++c) {
    int tile = c * 64 + lane;
    uint4 u = ST[tile][w ^ (tile & 7)];
    union { uint u; f16x2 h; } cv;
    cv.u = u.x; v[c * 8 + 0] = (float)cv.h.x; v[c * 8 + 1] = (float)cv.h.y;
    cv.u = u.y; v[c * 8 + 2] = (float)cv.h.x; v[c * 8 + 3] = (float)cv.h.y;
    cv.u = u.z; v[c * 8 + 4] = (float)cv.h.x; v[c * 8 + 5] = (float)cv.h.y;
    cv.u = u.w; v[c * 8 + 6] = (float)cv.h.x; v[c * 8 + 7] = (float)cv.h.y;
  }

  float4 fv = *(const float4*)(f   + (size_t)row * D_DIM + lane * 4);
  float4 cv4 = *(const float4*)(cen + (size_t)lab * D_DIM + lane * 4);
  float pv = fv.x * cv4.x + fv.y * cv4.y + fv.z * cv4.z + fv.w * cv4.w;

  float m = v[0];
#pragma unroll
  for (int k = 1; k < 64; ++k) m = fmaxf(m, v[k]);
#pragma unroll
  for (int o = 32; o > 0; o >>= 1) {
    m = fmaxf(m, __shfl_xor(m, o));
    pv += __shfl_xor(pv, o);
  }
  const float pos = pv;

  // bisection seeded at the row max key: answer lies within ~300 keys; 2048 is ample
  __half hm = __float2half(m);
  int hb = (int)(*(ushort*)&hm);
  int km = (m >= 0.f) ? (0x8000 | hb) : (~hb & 0xFFFF);
  int lo = km - 2048, hi = km;
  if (lo < 0x0400) lo = 0x0400;
  for (int it = 0; it < 12; ++it) {
    int mid = (lo + hi) >> 1;
    float tau = dec_key(mid);
    int c = 0;
#pragma unroll
    for (int k = 0; k < 64; ++k) c += (v[k] > tau) ? 1 : 0;
#pragma unroll
    for (int o = 32; o > 0; o >>= 1) c += __shfl_xor(c, o);
    if (c <= 49) hi = mid; else lo = mid + 1;
  }

  const float tau = dec_key(hi);
  float sum = 0.f, se = 0.f; int c = 0;
#pragma unroll
  for (int k = 0; k < 64; ++k) {
    if (v[k] > tau) { ++c; sum += v[k]; se += expf(v[k] - m); }
  }
#pragma unroll
  for (int o = 32; o > 0; o >>= 1) {
    sum += __shfl_xor(sum, o);
    se  += __shfl_xor(se, o);
    c   += __shfl_xor(c, o);
  }
  if (lane == 0) {
    float nfill = (float)(N_NEG - c);
    float S = sum + nfill * tau;
    float E = se + nfill * expf(tau - m);
    float M = fmaxf(m, pos);
    float seAll = E * expf(m - M) + expf(pos - M);
    float lse = M + logf(seAll);
    sblk[w] = 0.9102f * lse - 0.9002f * pos - 2.0e-4f * S;
  }
  __syncthreads();
  if (tid == 0) {
    float part = 0.f;
#pragma unroll
    for (int i = 0; i < 8; ++i) part += sblk[i];
    atomicAdd(accum, part);
    __threadfence();
    unsigned int old = atomicAdd(counter, 1u);
    if (old == gridDim.x - 1) {
      float s = atomicAdd(accum, 0.0f);   // atomic read: sees all prior adds
      out[0] = s * (1.0f / B_ROWS);
    }
  }
}

extern "C" void kernel_launch(void* const* d_in, const int* in_sizes, int n_in,
                              void* d_out, int out_size, void* d_ws, size_t ws_size,
                              hipStream_t stream) {
  const float* f   = (const float*)d_in[0];
  const float* cen = (const float*)d_in[1];
  const int*   label = (const int*)d_in[2];
  float* out = (float*)d_out;

  char* ws = (char*)d_ws;
  ushort* cand    = (ushort*)ws;                      // 16 MiB: [512 tiles][2048 rows][8] fp16
  ushort* fb      = (ushort*)(ws + 16777216);         // 1 MiB
  float*  accum   = (float*)(ws + 17825792);          // 4 B loss accumulator
  unsigned int* counter = (unsigned int*)(ws + 17825796);  // 4 B completion counter
  ushort* cb      = (ushort*)(ws + 17833984);         // 32 MiB (fast path)
  const bool pre = ws_size >= (17833984ull + 33554432ull);

  dim3 grid(B_ROWS / 128, NTILES);  // XCD-chunk swizzled inside the kernel
  if (pre) {
    cvt_all<<<8448, 256, 0, stream>>>(f, fb, cen, cb, accum, counter);
    gemm_reduce<true><<<grid, 256, 0, stream>>>(fb, cb, nullptr, label, cand);
  } else {
    cvt_all<<<256, 256, 0, stream>>>(f, fb, nullptr, nullptr, accum, counter);
    gemm_reduce<false><<<grid, 256, 0, stream>>>(fb, nullptr, cen, label, cand);
  }

  final_select<<<B_ROWS / 8, 512, 0, stream>>>(cand, f, cen, label, accum, counter, out);
}

// Round 9
// 186.498 us; speedup vs baseline: 1.1811x; 1.0158x over previous
//
#include <hip/hip_runtime.h>
#include <hip/hip_fp16.h>

#define B_ROWS 2048
#define C_COLS 65536
#define D_DIM  256
#define N_NEG  50
#define NTILES (C_COLS / 128)   // 512 column vtiles (cand layout unit)

typedef __attribute__((ext_vector_type(8))) short short8;
typedef __attribute__((ext_vector_type(4))) float floatx4;
typedef __fp16 f16x2 __attribute__((ext_vector_type(2)));

__device__ __forceinline__ ushort f2bf(float f) {
  unsigned u = __float_as_uint(f);
  unsigned r = (u + 0x7FFFu + ((u >> 16) & 1u)) >> 16;  // RNE
  return (ushort)r;
}

__device__ __forceinline__ uint hmax2(uint a, uint b) {
  union { uint u; f16x2 h; } x, y, r;
  x.u = a; y.u = b;
  r.h = __builtin_elementwise_max(x.h, y.h);
  return r.u;
}

// ---------------- fp32 -> bf16 convert, K-block XOR swizzle in global layout ----
__device__ __forceinline__ void cvt8(const float* __restrict__ in, ushort* __restrict__ out,
                                     int i) {
  int row = i >> 5;
  int ka  = i & 31;
  int ktile = ka >> 3, kb = ka & 7;
  const float4* src = (const float4*)(in + (size_t)i * 8);
  float4 a = src[0], b = src[1];
  ushort4 o0, o1;
  o0.x = f2bf(a.x); o0.y = f2bf(a.y); o0.z = f2bf(a.z); o0.w = f2bf(a.w);
  o1.x = f2bf(b.x); o1.y = f2bf(b.y); o1.z = f2bf(b.z); o1.w = f2bf(b.w);
  ushort* dst = out + (size_t)row * D_DIM + ktile * 64 + ((kb ^ (row & 7)) << 3);
  ((ushort4*)dst)[0] = o0;
  ((ushort4*)dst)[1] = o1;
}

// one dispatch: blocks [0,256) convert f -> fb, blocks [256,8448) convert cen -> cb.
// block 0 also zero-inits the loss accumulator + completion counter.
__global__ void cvt_all(const float* __restrict__ f, ushort* __restrict__ fb,
                        const float* __restrict__ cen, ushort* __restrict__ cb,
                        float* __restrict__ accum, unsigned int* __restrict__ counter) {
  const int b = blockIdx.x, tid = threadIdx.x;
  if (b == 0 && tid == 0) { *accum = 0.f; *counter = 0u; }
  if (b < 256) {
    int i = b * 256 + tid;
    if (i < (B_ROWS * D_DIM) / 8) cvt8(f, fb, i);
  } else {
    int i = (b - 256) * 256 + tid;
    if (i < (C_COLS * D_DIM) / 8) cvt8(cen, cb, i);
  }
}

__device__ __forceinline__ void async16(const void* g, void* l) {
  __builtin_amdgcn_global_load_lds((const __attribute__((address_space(1))) void*)g,
                                   (__attribute__((address_space(3))) void*)l,
                                   16, 0, 0);
}

// ---------------- GEMM (D[n][m]) + in-register 16:1 group-max reduction ----------------
// 256n x 128m tile, 512 thr (8 waves as 4n x 2m, each 64x64 = R8's exact wave tile).
// Single-buffered 48KB LDS, 2-barrier K-loop; staging traffic 786MB (-25% vs R8's 1.05GB),
// barrier events halved (4096 blocks). Epilogue identical reduce; block writes cand
// vtiles 2T and 2T+1 so final_select is unchanged.
template <bool PREB>
__global__ __launch_bounds__(512) void gemm_reduce(const ushort* __restrict__ fb,
                                                   const ushort* __restrict__ cb,
                                                   const float* __restrict__ cen,
                                                   const int* __restrict__ label,
                                                   ushort* __restrict__ cand) {
  __shared__ __align__(16) ushort Cs[256 * 64];   // cen bf16 [256][64], swizzled kblks (32KB)
  __shared__ __align__(16) ushort Fs[128 * 64];   // f   bf16 [128][64], swizzled kblks (16KB)

  const int tid = threadIdx.x, wave = tid >> 6, lane = tid & 63;
  const int l = lane & 15, q = lane >> 4;

  // bijective XCD-chunk remap (4096 blocks, 8 XCDs x 512; slab-fastest inside)
  const int lin = blockIdx.x;
  const int lg  = (lin & 7) * 512 + (lin >> 3);
  const int m0 = (lg & 15) << 7;          // 16 m-slabs of 128
  const int T  = lg >> 4;                 // 256 n-tiles of 256
  const int n0 = T << 8;

  floatx4 acc[4][4] = {};                 // [i: n-frag][j: m-frag]
  const int wn = (wave & 3) * 64, wm = (wave >> 2) * 64;

  for (int kt = 0; kt < D_DIM / 64; ++kt) {
    // f: 16KB, 2 loads/thread
#pragma unroll
    for (int r = 0; r < 2; ++r) {
      int idx = r * 4096 + wave * 512 + lane * 8;
      int row = idx >> 6, kk = idx & 63;
      async16(fb + (size_t)(m0 + row) * D_DIM + kt * 64 + kk, Fs + r * 4096 + wave * 512);
    }
    if (PREB) {
      // cen: 32KB, 4 loads/thread
#pragma unroll
      for (int r = 0; r < 4; ++r) {
        int idx = r * 4096 + wave * 512 + lane * 8;
        int row = idx >> 6, kk = idx & 63;
        async16(cb + (size_t)(n0 + row) * D_DIM + kt * 64 + kk, Cs + r * 4096 + wave * 512);
      }
    } else {
      float4 ra[4], rb[4];
#pragma unroll
      for (int g = 0; g < 4; ++g) {
        int e = (tid + g * 512) * 8;
        const float* gp = cen + (size_t)(n0 + (e >> 6)) * D_DIM + kt * 64 + (e & 63);
        ra[g] = *(const float4*)gp;
        rb[g] = *(const float4*)(gp + 4);
      }
#pragma unroll
      for (int g = 0; g < 4; ++g) {
        int e = (tid + g * 512) * 8;
        int row = e >> 6, kblk = (e >> 3) & 7;
        uint4 o;
        o.x = (uint)f2bf(ra[g].x) | ((uint)f2bf(ra[g].y) << 16);
        o.y = (uint)f2bf(ra[g].z) | ((uint)f2bf(ra[g].w) << 16);
        o.z = (uint)f2bf(rb[g].x) | ((uint)f2bf(rb[g].y) << 16);
        o.w = (uint)f2bf(rb[g].z) | ((uint)f2bf(rb[g].w) << 16);
        *(uint4*)(Cs + (row << 6) + ((kblk ^ (row & 7)) << 3)) = o;
      }
    }
    __syncthreads();

#pragma unroll
    for (int ks = 0; ks < 2; ++ks) {
      short8 a[4], b[4];
#pragma unroll
      for (int i = 0; i < 4; ++i) {
        int swz = ((4 * ks + q) ^ (l & 7)) << 3;
        a[i] = *(const short8*)(Cs + ((wn + i * 16 + l) << 6) + swz);
        b[i] = *(const short8*)(Fs + ((wm + i * 16 + l) << 6) + swz);
      }
#pragma unroll
      for (int i = 0; i < 4; ++i)
#pragma unroll
        for (int j = 0; j < 4; ++j)
          acc[i][j] = __builtin_amdgcn_mfma_f32_16x16x32_bf16(a[i], b[j], acc[i][j], 0, 0, 0);
    }
    __syncthreads();
  }

  // ---- epilogue: in-register label mask + 16:1 group-max, reg->global ----
  // lane holds D[n][m]: n_local = wn + i*16 + q*4 + r, m_local = wm + j*16 + l.
  int lj[4];
#pragma unroll
  for (int j = 0; j < 4; ++j) lj[j] = label[m0 + wm + j * 16 + l] - n0 - wn;
  bool hit = false;
#pragma unroll
  for (int j = 0; j < 4; ++j) hit = hit || ((unsigned)lj[j] < 64u);
  if (__any(hit)) {            // rare: mask positive column pre-max
#pragma unroll
    for (int j = 0; j < 4; ++j) {
      int relq = lj[j] - q * 4;
#pragma unroll
      for (int i = 0; i < 4; ++i) {
        int rel = relq - i * 16;
#pragma unroll
        for (int r = 0; r < 4; ++r)
          if (rel == r) acc[i][j][r] = -INFINITY;
      }
    }
  }
  // frag (i,j) covers group (wn>>4)+i for 16 m's; reduce 4 regs in-lane, then across q.
#pragma unroll
  for (int j = 0; j < 4; ++j) {
    float mx[4];
#pragma unroll
    for (int i = 0; i < 4; ++i)
      mx[i] = fmaxf(fmaxf(acc[i][j][0], acc[i][j][1]),
                    fmaxf(acc[i][j][2], acc[i][j][3]));
    union { f16x2 h; uint u; } c0, c1;
    c0.h = __builtin_amdgcn_cvt_pkrtz(mx[0], mx[1]);
    c1.h = __builtin_amdgcn_cvt_pkrtz(mx[2], mx[3]);
    uint u01 = c0.u, u23 = c1.u;
    u01 = hmax2(u01, __shfl_xor(u01, 16));
    u01 = hmax2(u01, __shfl_xor(u01, 32));
    u23 = hmax2(u23, __shfl_xor(u23, 16));
    u23 = hmax2(u23, __shfl_xor(u23, 32));
    if (q == 0) {
      uint2 w; w.x = u01; w.y = u23;
      // vtile = 2T + (wn>=128); 4-group half within vtile = (wn&64)>>4 ushorts.
      const int vtile = 2 * T + (wn >> 7);
      *(uint2*)(cand + ((size_t)vtile * B_ROWS + m0 + wm + j * 16 + l) * 8 +
                ((wn & 64) >> 4)) = w;
    }
  }
}

// fp16-bit monotone key <-> value
__device__ __forceinline__ float dec_key(int k) {
  if (k < 0x0400) return -INFINITY;
  ushort h = (k >= 0x8000) ? (ushort)(k ^ 0x8000) : (ushort)(~k & 0xFFFF);
  __half_raw hr; hr.x = h;
  return __half2float((__half)hr);
}

// ---------------- per-row top-50 + loss (one wave/row) + fused grid reduction ----
__global__ __launch_bounds__(512) void final_select(const ushort* __restrict__ cand,
                                                    const float* __restrict__ f,
                                                    const float* __restrict__ cen,
                                                    const int* __restrict__ label,
                                                    float* __restrict__ accum,
                                                    unsigned int* __restrict__ counter,
                                                    float* __restrict__ out) {
  __shared__ __align__(16) uint4 ST[NTILES][8];   // 64 KB, slot swizzled by tile&7
  __shared__ float sblk[8];
  const int tid = threadIdx.x;
  const int lane = tid & 63, w = tid >> 6;
  const int row0 = blockIdx.x * 8;

  const uint4* p = (const uint4*)cand;
#pragma unroll
  for (int k = 0; k < 8; ++k) {
    int j = k * 512 + tid;
    int tile = j >> 3, rr = j & 7;
    ST[tile][rr ^ (tile & 7)] = p[(size_t)tile * B_ROWS + row0 + rr];
  }
  __syncthreads();

  const int row = row0 + w;
  const int lab = label[row];

  float v[64];
#pragma unroll
  for (int c = 0; c < 8; ++c) {
    int tile = c * 64 + lane;
    uint4 u = ST[tile][w ^ (tile & 7)];
    union { uint u; f16x2 h; } cv;
    cv.u = u.x; v[c * 8 + 0] = (float)cv.h.x; v[c * 8 + 1] = (float)cv.h.y;
    cv.u = u.y; v[c * 8 + 2] = (float)cv.h.x; v[c * 8 + 3] = (float)cv.h.y;
    cv.u = u.z; v[c * 8 + 4] = (float)cv.h.x; v[c * 8 + 5] = (float)cv.h.y;
    cv.u = u.w; v[c * 8 + 6] = (float)cv.h.x; v[c * 8 + 7] = (float)cv.h.y;
  }

  float4 fv = *(const float4*)(f   + (size_t)row * D_DIM + lane * 4);
  float4 cv4 = *(const float4*)(cen + (size_t)lab * D_DIM + lane * 4);
  float pv = fv.x * cv4.x + fv.y * cv4.y + fv.z * cv4.z + fv.w * cv4.w;

  float m = v[0];
#pragma unroll
  for (int k = 1; k < 64; ++k) m = fmaxf(m, v[k]);
#pragma unroll
  for (int o = 32; o > 0; o >>= 1) {
    m = fmaxf(m, __shfl_xor(m, o));
    pv += __shfl_xor(pv, o);
  }
  const float pos = pv;

  // bisection seeded at the row max key: answer lies within ~300 keys; 2048 is ample
  __half hm = __float2half(m);
  int hb = (int)(*(ushort*)&hm);
  int km = (m >= 0.f) ? (0x8000 | hb) : (~hb & 0xFFFF);
  int lo = km - 2048, hi = km;
  if (lo < 0x0400) lo = 0x0400;
  for (int it = 0; it < 12; ++it) {
    int mid = (lo + hi) >> 1;
    float tau = dec_key(mid);
    int c = 0;
#pragma unroll
    for (int k = 0; k < 64; ++k) c += (v[k] > tau) ? 1 : 0;
#pragma unroll
    for (int o = 32; o > 0; o >>= 1) c += __shfl_xor(c, o);
    if (c <= 49) hi = mid; else lo = mid + 1;
  }

  const float tau = dec_key(hi);
  float sum = 0.f, se = 0.f; int c = 0;
#pragma unroll
  for (int k = 0; k < 64; ++k) {
    if (v[k] > tau) { ++c; sum += v[k]; se += expf(v[k] - m); }
  }
#pragma unroll
  for (int o = 32; o > 0; o >>= 1) {
    sum += __shfl_xor(sum, o);
    se  += __shfl_xor(se, o);
    c   += __shfl_xor(c, o);
  }
  if (lane == 0) {
    float nfill = (float)(N_NEG - c);
    float S = sum + nfill * tau;
    float E = se + nfill * expf(tau - m);
    float M = fmaxf(m, pos);
    float seAll = E * expf(m - M) + expf(pos - M);
    float lse = M + logf(seAll);
    sblk[w] = 0.9102f * lse - 0.9002f * pos - 2.0e-4f * S;
  }
  __syncthreads();
  if (tid == 0) {
    float part = 0.f;
#pragma unroll
    for (int i = 0; i < 8; ++i) part += sblk[i];
    atomicAdd(accum, part);
    __threadfence();
    unsigned int old = atomicAdd(counter, 1u);
    if (old == gridDim.x - 1) {
      float s = atomicAdd(accum, 0.0f);   // atomic read: sees all prior adds
      out[0] = s * (1.0f / B_ROWS);
    }
  }
}

extern "C" void kernel_launch(void* const* d_in, const int* in_sizes, int n_in,
                              void* d_out, int out_size, void* d_ws, size_t ws_size,
                              hipStream_t stream) {
  const float* f   = (const float*)d_in[0];
  const float* cen = (const float*)d_in[1];
  const int*   label = (const int*)d_in[2];
  float* out = (float*)d_out;

  char* ws = (char*)d_ws;
  ushort* cand    = (ushort*)ws;                      // 16 MiB: [512 vtiles][2048 rows][8] fp16
  ushort* fb      = (ushort*)(ws + 16777216);         // 1 MiB
  float*  accum   = (float*)(ws + 17825792);          // 4 B loss accumulator
  unsigned int* counter = (unsigned int*)(ws + 17825796);  // 4 B completion counter
  ushort* cb      = (ushort*)(ws + 17833984);         // 32 MiB (fast path)
  const bool pre = ws_size >= (17833984ull + 33554432ull);

  if (pre) {
    cvt_all<<<8448, 256, 0, stream>>>(f, fb, cen, cb, accum, counter);
    gemm_reduce<true><<<4096, 512, 0, stream>>>(fb, cb, nullptr, label, cand);
  } else {
    cvt_all<<<256, 256, 0, stream>>>(f, fb, nullptr, nullptr, accum, counter);
    gemm_reduce<false><<<4096, 512, 0, stream>>>(fb, nullptr, cen, label, cand);
  }

  final_select<<<B_ROWS / 8, 512, 0, stream>>>(cand, f, cen, label, accum, counter, out);
}